// Round 10
// baseline (975.487 us; speedup 1.0000x reference)
//
#include <hip/hip_runtime.h>
#include <cstdint>
#include <cstddef>

// Mix9Net trunk via MFMA, v4: no LDS weight staging. A-fragments load f16
// weights straight from d_ws (L2-resident, coalesced 16B/lane, identical
// across blocks). Barriers only around h-grid updates (2/layer). Activations
// f16 in a 17x16+1 packed padded grid (HW-verified v2/v3). Output staged
// through LDS and streamed as full-line float4 stores (no RFO).

#define HWX 15
#define NPOS 225
#define CH 128
#define NTH 256
#define GRID_SLOTS 273                 // 17 rows x 16 cols + 1 tail
#define LDS_BYTES (GRID_SLOTS*256)     // 69,888 B -> 2 blocks/CU
#define SAFE_PP 136

// d_ws f16 element offsets
#define WSE_WDC 0                      // 48 blks [128][32]: (res*3+tap)*4+ks
#define WSE_WC1 196608                 // 16 blks: res*4+ks
#define WSE_W01 262144                 // 4 blks
#define WSE_W02 278528                 // 4 blks
#define WSE_WF  294912                 // 4 blks [64][32]
#define WSE_W0  303104                 // 3 blks [128][32] (k>=2 zero): tap
#define WSE_TOTAL 315392
#define WS_NEED (WSE_TOTAL*2)

typedef _Float16 f16;
typedef __attribute__((ext_vector_type(8))) _Float16 f16x8;
typedef __attribute__((ext_vector_type(4))) _Float16 f16x4;
typedef __attribute__((ext_vector_type(4))) float f32x4;

// h-grid: [pp][128ch] f16, 256 B/slot, XOR swizzle on (pp&15).
// B-frag reads conflict-free per 16-lane phase (derived r6, verified v2/v3).
__device__ __forceinline__ int hb_addr(int pp, int k){
  return pp*256 + ((k*2) ^ ((pp&15)<<4));
}
__device__ __forceinline__ float silu_f(float v){ return v / (1.f + __expf(-v)); }

// One K=32 GEMM step. A direct from global (f16 ws or f32 fallback).
// A-frag: W[mt*16+col][krow*8+j]; B-frag: h[ks+krow*8+j][pos].
// D: col=lane&15 (pos), row=krow*4+reg (out-ch)  [m89-verified]
template<int MT, bool WS>
__device__ __forceinline__ void gemm_k32(const char* sm, const f16* __restrict__ wsblk,
    const float* __restrict__ f32w, const int* pbt, int ksabs, int krow, int col,
    f32x4 acc[4][8]){
  const int kb = ksabs + krow*8;
  const int k8 = krow*8;
  f16x8 b0 = *(const f16x8*)(sm + hb_addr(pbt[0], kb));
  f16x8 b1 = *(const f16x8*)(sm + hb_addr(pbt[1], kb));
  f16x8 b2 = *(const f16x8*)(sm + hb_addr(pbt[2], kb));
  f16x8 b3 = *(const f16x8*)(sm + hb_addr(pbt[3], kb));
#pragma unroll
  for (int mt=0; mt<MT; mt++){
    const int o = mt*16 + col;
    f16x8 a;
    if (WS){
      a = *(const f16x8*)(wsblk + o*32 + k8);
    } else {
      const float* s = f32w + (size_t)o*CH + ksabs + k8;
      float4 x0 = *(const float4*)(s), x1 = *(const float4*)(s+4);
      a = (f16x8){(f16)x0.x,(f16)x0.y,(f16)x0.z,(f16)x0.w,
                  (f16)x1.x,(f16)x1.y,(f16)x1.z,(f16)x1.w};
    }
    acc[0][mt] = __builtin_amdgcn_mfma_f32_16x16x32_f16(a, b0, acc[0][mt], 0,0,0);
    acc[1][mt] = __builtin_amdgcn_mfma_f32_16x16x32_f16(a, b1, acc[1][mt], 0,0,0);
    acc[2][mt] = __builtin_amdgcn_mfma_f32_16x16x32_f16(a, b2, acc[2][mt], 0,0,0);
    acc[3][mt] = __builtin_amdgcn_mfma_f32_16x16x32_f16(a, b3, acc[3][mt], 0,0,0);
  }
}

// Full K=128 pass: 4 K=32 steps, no barriers (acc-chain ILP + vmcnt pipelining).
template<int MT, bool WS>
__device__ __forceinline__ void pass128(const char* sm, const f16* __restrict__ wsbase,
    int blkElems, const float* __restrict__ f32w, const int* pbt, int krow, int col,
    f32x4 acc[4][8]){
#pragma unroll
  for (int kq=0; kq<4; kq++)
    gemm_k32<MT,WS>(sm, wsbase + (size_t)kq*blkElems, f32w, pbt, kq*32, krow, col, acc);
}

// Layer-0 K=32 step (x has 2 channels; ws blocks zero-padded; f32 path guards).
template<bool WS>
__device__ __forceinline__ void gemm_l0(const char* sm, const f16* __restrict__ wsblk,
    const float* __restrict__ w0tap, const int* pbt, int krow, int col, f32x4 acc[4][8]){
  const int kb = krow*8;
  f16x8 b0 = *(const f16x8*)(sm + hb_addr(pbt[0], kb));
  f16x8 b1 = *(const f16x8*)(sm + hb_addr(pbt[1], kb));
  f16x8 b2 = *(const f16x8*)(sm + hb_addr(pbt[2], kb));
  f16x8 b3 = *(const f16x8*)(sm + hb_addr(pbt[3], kb));
#pragma unroll
  for (int mt=0; mt<8; mt++){
    const int o = mt*16 + col;
    f16x8 a;
    if (WS){
      a = *(const f16x8*)(wsblk + o*32 + kb);
    } else {
      a = (f16x8){(f16)0,(f16)0,(f16)0,(f16)0,(f16)0,(f16)0,(f16)0,(f16)0};
      if (krow == 0){
        float2 w = *(const float2*)(w0tap + o*2);
        a[0] = (f16)w.x; a[1] = (f16)w.y;
      }
    }
    acc[0][mt] = __builtin_amdgcn_mfma_f32_16x16x32_f16(a, b0, acc[0][mt], 0,0,0);
    acc[1][mt] = __builtin_amdgcn_mfma_f32_16x16x32_f16(a, b1, acc[1][mt], 0,0,0);
    acc[2][mt] = __builtin_amdgcn_mfma_f32_16x16x32_f16(a, b2, acc[2][mt], 0,0,0);
    acc[3][mt] = __builtin_amdgcn_mfma_f32_16x16x32_f16(a, b3, acc[3][mt], 0,0,0);
  }
}

__device__ __forceinline__ void zacc_all(f32x4 acc[4][8]){
#pragma unroll
  for (int t=0;t<4;t++)
#pragma unroll
    for (int m=0;m<8;m++) acc[t][m] = (f32x4){0.f,0.f,0.f,0.f};
}

__device__ __forceinline__ void snap4x8(const char* sm, f16x4 r[4][8],
                                        const int* pbs, int krow){
#pragma unroll
  for (int t=0;t<4;t++)
#pragma unroll
    for (int mt=0;mt<8;mt++)
      r[t][mt] = *(const f16x4*)(sm + hb_addr(pbs[t], mt*16 + krow*4));
}

template<int MT, bool SILU, bool RES>
__device__ __forceinline__ void wb4(char* sm, f32x4 acc[4][8],
                                    const float* __restrict__ bias,
                                    f16x4 rsd[4][8], const int* pbs,
                                    const bool* val, int krow){
#pragma unroll
  for (int mt=0;mt<MT;mt++){
    const int ch0 = mt*16 + krow*4;
    float4 bb = *(const float4*)(bias + ch0);
    const float bj[4] = {bb.x, bb.y, bb.z, bb.w};
#pragma unroll
    for (int t=0;t<4;t++){
      f32x4 v = acc[t][mt];
#pragma unroll
      for (int j=0;j<4;j++) v[j] += bj[j];
      if (SILU){
#pragma unroll
        for (int j=0;j<4;j++) v[j] = silu_f(v[j]);
      }
      if (RES){
        f16x4 r = rsd[t][mt];
#pragma unroll
        for (int j=0;j<4;j++) v[j] += (float)r[j];
      }
      if (val[t]){
        f16x4 o = { (f16)v[0],(f16)v[1],(f16)v[2],(f16)v[3] };
        *(f16x4*)(sm + hb_addr(pbs[t], ch0)) = o;
      }
    }
  }
}

struct P {
  const float *x, *w0, *b0, *wdc, *bdc, *wc1, *bc1, *w01, *b01, *w02, *b02, *wf, *bf;
};

template<bool WS>
__global__ __launch_bounds__(NTH, 2)
void mix9_v4(const P p, const f16* __restrict__ wsf, float* __restrict__ out)
{
  __shared__ char sm[LDS_BYTES];
  const int tid  = threadIdx.x;
  const int lane = tid & 63;
  const int wave = tid >> 6;
  const int col  = lane & 15;
  const int krow = lane >> 4;
  const int d = blockIdx.x & 3;
  const int b = blockIdx.x >> 2;

  // zero h grid (pads + unused channels must stay 0)
  for (int i = tid; i < LDS_BYTES/16; i += NTH)
    ((f32x4*)sm)[i] = (f32x4){0.f,0.f,0.f,0.f};
  __syncthreads();

  // stage x (2 channels) into h-grid channels 0,1
  for (int i = tid; i < 2*NPOS; i += NTH){
    const int ic = i/NPOS, n = i%NPOS;
    const int pp = (n/HWX + 1)*16 + (n%HWX + 1);
    *(f16*)(sm + hb_addr(pp, ic)) = (f16)p.x[(size_t)b*2*NPOS + i];
  }
  __syncthreads();

  int pbs[4]; bool val[4];
#pragma unroll
  for (int t=0;t<4;t++){
    const int r = wave*4 + t;                 // 0..15 (15 = dead tile)
    val[t] = (col >= 1) && (r < HWX);
    pbs[t] = val[t] ? (r+1)*16 + col : SAFE_PP;
  }
  int dneg;
  switch (d){
    case 0:  dneg = -1;  break;   // horiz (0,-1)
    case 1:  dneg = -16; break;   // vert  (-1,0)
    case 2:  dneg = -17; break;   // diag  (-1,-1)
    default: dneg =  15; break;   // anti  (+1,-1)
  }

  f32x4 acc[4][8];
  f16x4 rsd[4][8];

  // ---- layer 0: h = silu(dconv0(x)) ----
  zacc_all(acc);
#pragma unroll 1
  for (int k=0;k<3;k++){
    const int sh = (k==0) ? dneg : (k==1) ? 0 : -dneg;
    int pbt[4];
#pragma unroll
    for (int t=0;t<4;t++) pbt[t] = pbs[t] + sh;
    gemm_l0<WS>(sm, wsf + WSE_W0 + (size_t)k*4096, p.w0 + (size_t)k*CH*2,
                pbt, krow, col, acc);
  }
  __syncthreads();                     // all x reads done before h overwrite
  wb4<8,true,false>(sm, acc, p.b0, nullptr, pbs, val, krow);
  __syncthreads();

  // ---- 4 directional res blocks ----
#pragma unroll 1
  for (int res=0; res<4; res++){
    zacc_all(acc);
#pragma unroll 1
    for (int k=0;k<3;k++){
      const int sh = (k==0) ? dneg : (k==1) ? 0 : -dneg;
      int pbt[4];
#pragma unroll
      for (int t=0;t<4;t++) pbt[t] = pbs[t] + sh;
      pass128<8,WS>(sm, wsf + WSE_WDC + (size_t)(res*3+k)*4*4096, 4096,
                    p.wdc + (size_t)(res*3+k)*CH*CH, pbt, krow, col, acc);
    }
    __syncthreads();                   // all B-reads of h done
    snap4x8(sm, rsd, pbs, krow);       // residual = pre-dconv h (own slots)
    wb4<8,true,false>(sm, acc, p.bdc + res*CH, nullptr, pbs, val, krow);
    __syncthreads();

    zacc_all(acc);
    pass128<8,WS>(sm, wsf + WSE_WC1 + (size_t)res*4*4096, 4096,
                  p.wc1 + (size_t)res*CH*CH, pbs, krow, col, acc);
    __syncthreads();
    wb4<8,true,true>(sm, acc, p.bc1 + res*CH, rsd, pbs, val, krow);
    __syncthreads();
  }

  // ---- Conv0dResBlock ----
  zacc_all(acc);
  pass128<8,WS>(sm, wsf + WSE_W01, 4096, p.w01, pbs, krow, col, acc);
  __syncthreads();
  snap4x8(sm, rsd, pbs, krow);
  wb4<8,true,false>(sm, acc, p.b01, nullptr, pbs, val, krow);
  __syncthreads();

  zacc_all(acc);
  pass128<8,WS>(sm, wsf + WSE_W02, 4096, p.w02, pbs, krow, col, acc);
  __syncthreads();
  wb4<8,true,true>(sm, acc, p.b02, rsd, pbs, val, krow);
  __syncthreads();

  // ---- final 1x1: 128 -> 64 (+bias) ----
  zacc_all(acc);
  pass128<4,WS>(sm, wsf + WSE_WF, 2048, p.wf, pbs, krow, col, acc);
  __syncthreads();                     // all h reads done; reuse LDS for out

  // stage fp32 output [64][225] in LDS, then stream full lines to global
  float* osm = (float*)sm;
#pragma unroll
  for (int t=0;t<4;t++){
    if (val[t]){
      const int r = wave*4 + t;
      const int n = r*HWX + (col-1);
#pragma unroll
      for (int mt=0;mt<4;mt++){
        const int ch0 = mt*16 + krow*4;
        float4 bb = *(const float4*)(p.bf + ch0);
        osm[(ch0+0)*NPOS + n] = acc[t][mt][0] + bb.x;
        osm[(ch0+1)*NPOS + n] = acc[t][mt][1] + bb.y;
        osm[(ch0+2)*NPOS + n] = acc[t][mt][2] + bb.z;
        osm[(ch0+3)*NPOS + n] = acc[t][mt][3] + bb.w;
      }
    }
  }
  __syncthreads();
  float* ob = out + (size_t)(b*4 + d)*64*NPOS;
  for (int i = tid; i < (64*NPOS)/4; i += NTH)
    *(float4*)(ob + i*4) = *(const float4*)(osm + i*4);
}

// Converter: f32 weights -> f16 d_ws, [block][o][k32] plain rows.
__global__ void cvt_ws(const P p, f16* __restrict__ ws)
{
  const int idx = blockIdx.x*NTH + threadIdx.x;
  if (idx >= WSE_TOTAL) return;
  float v;
  if (idx < WSE_WC1){
    int blk = idx >> 12, rem = idx & 4095;
    int o = rem >> 5, k = rem & 31;
    int ks = blk & 3, tapres = blk >> 2;          // res*3+tap
    v = p.wdc[((size_t)tapres*CH + o)*CH + ks*32 + k];
  } else if (idx < WSE_W01){
    int j = idx - WSE_WC1;
    int blk = j >> 12, rem = j & 4095;
    int o = rem >> 5, k = rem & 31;
    int ks = blk & 3, res = blk >> 2;
    v = p.wc1[((size_t)res*CH + o)*CH + ks*32 + k];
  } else if (idx < WSE_W02){
    int j = idx - WSE_W01;
    int ks = j >> 12, rem = j & 4095;
    int o = rem >> 5, k = rem & 31;
    v = p.w01[(size_t)o*CH + ks*32 + k];
  } else if (idx < WSE_WF){
    int j = idx - WSE_W02;
    int ks = j >> 12, rem = j & 4095;
    int o = rem >> 5, k = rem & 31;
    v = p.w02[(size_t)o*CH + ks*32 + k];
  } else if (idx < WSE_W0){
    int j = idx - WSE_WF;
    int ks = j >> 11, rem = j & 2047;
    int o = rem >> 5, k = rem & 31;
    v = p.wf[(size_t)o*CH + ks*32 + k];
  } else {
    int j = idx - WSE_W0;
    int tap = j >> 12, rem = j & 4095;
    int o = rem >> 5, k = rem & 31;
    v = (k < 2) ? p.w0[((size_t)tap*CH + o)*2 + k] : 0.f;
  }
  ws[idx] = (f16)v;
}

extern "C" void kernel_launch(void* const* d_in, const int* in_sizes, int n_in,
                              void* d_out, int out_size, void* d_ws, size_t ws_size,
                              hipStream_t stream)
{
  (void)in_sizes; (void)n_in; (void)out_size;
  P p;
  p.x   = (const float*)d_in[0];
  p.w0  = (const float*)d_in[1];   // [3][128][2]
  p.b0  = (const float*)d_in[2];
  p.wdc = (const float*)d_in[3];   // [4][3][128][128]
  p.bdc = (const float*)d_in[4];
  p.wc1 = (const float*)d_in[5];   // [4][128][128]
  p.bc1 = (const float*)d_in[6];
  p.w01 = (const float*)d_in[7];
  p.b01 = (const float*)d_in[8];
  p.w02 = (const float*)d_in[9];
  p.b02 = (const float*)d_in[10];
  p.wf  = (const float*)d_in[11];  // [64][128]
  p.bf  = (const float*)d_in[12];

  float* out = (float*)d_out;
  const bool ws_ok = (d_ws != nullptr) && (ws_size >= (size_t)WS_NEED);

  if (ws_ok){
    f16* ws = (f16*)d_ws;
    cvt_ws<<<dim3((WSE_TOTAL + NTH - 1)/NTH), dim3(NTH), 0, stream>>>(p, ws);
    mix9_v4<true><<<dim3(256*4), dim3(NTH), 0, stream>>>(p, ws, out);
  } else {
    mix9_v4<false><<<dim3(256*4), dim3(NTH), 0, stream>>>(p, nullptr, out);
  }
}